// Round 11
// baseline (78.213 us; speedup 1.0000x reference)
//
#include <hip/hip_runtime.h>

#define B_ 32
#define T_ 128
#define R_ 49
#define D_ 512
#define HE_ 256
#define HC_ 256

#define NG_PACK 64     // pack blocks folded into K1 (independent of k1 work)
#define NG_K1 512      // 8 tokens per block
#define NG_G1 177      // 128 wh-tiles + 49 rh-tiles (32 rows each)
#define NG_G2 128      // pscore GEMM tiles (32 rows each)
#define NG_NEGB 512    // neg-expert: one block per (b, 8-token tile)

typedef float f32x4 __attribute__((ext_vector_type(4)));
typedef short s16x8 __attribute__((ext_vector_type(8)));
typedef short s16x4 __attribute__((ext_vector_type(4)));

__device__ __forceinline__ unsigned short bf16rne(float f) {
  unsigned u = __float_as_uint(f);
  u += 0x7FFF + ((u >> 16) & 1);
  return (unsigned short)(u >> 16);
}
__device__ __forceinline__ float bf16tof(unsigned short h) {
  return __uint_as_float((unsigned)h << 16);
}
__device__ __forceinline__ float rcp_fast(float x) {
  return __builtin_amdgcn_rcpf(x);
}
__device__ __forceinline__ float tanh_fast(float x) {
  float e = __expf(2.0f * x);
  return fmaf(-2.0f, rcp_fast(e + 1.0f), 1.0f);
}
__device__ __forceinline__ float sigmoid_fast(float x) {
  return rcp_fast(1.0f + __expf(-x));
}
__device__ __forceinline__ float wave_sum(float v) {
#pragma unroll
  for (int off = 32; off; off >>= 1) v += __shfl_down(v, off);
  return v;  // total valid in lane 0
}

// ---------------------------------------------------------------------------
// K1: pack blocks (bid<64) + k1 blocks (attn/softmax/pos).
// R11: region[b] staged to LDS (bf16) during the attn pass; the pos phase
// reads LDS instead of issuing a SECOND 100KB global pass of 49
// latency-chained loads per thread (R9: k1 = 26.6us, 1.5 TB/s = NOT
// BW-bound, VALU 20% -> miss-latency-bound; R10's XCD swizzle was null, so
// the fix must remove the latency chain itself, not re-place it).
// Attn dot stays fp32 from global (hard 0.1 threshold bit-identical);
// only the pos einsum consumes bf16 region (pos already bf16-rounds into
// GEMM2; pagg path attenuates the ~1e-2 rounding well below absmax).
// ---------------------------------------------------------------------------
__global__ __launch_bounds__(512, 4) void k1_pack(
    const float* __restrict__ word, const float* __restrict__ region,
    const float* __restrict__ nw1, const float* __restrict__ pw1,
    const int* __restrict__ amask, unsigned short* __restrict__ wp,
    float* __restrict__ pos, float* __restrict__ negcnt,
    unsigned long long* __restrict__ nmask) {
  __shared__ float attn_s[8][52];
  __shared__ alignas(16) float wp_T[49][8];
  __shared__ alignas(16) unsigned short regs_bf[R_ * D_];  // 50.2 KB
  int tid = threadIdx.x, wave = tid >> 6, lane = tid & 63;
  int bid = blockIdx.x;

  if (bid < NG_PACK) {
    int gid = bid * 512 + tid;  // 0..32767
    int mat = gid >> 14;
    int rem = gid & 16383;
    int plane = rem & 63;
    int tile = rem >> 6;
    int kt = tile >> 4, ct = tile & 15;
    const float* W = mat ? pw1 : nw1;
    int k0 = kt * 32 + (plane >> 4) * 8;
    int c = ct * 16 + (plane & 15);
    s16x8 pk;
#pragma unroll
    for (int j = 0; j < 8; ++j)
      pk[j] = (short)bf16rne(W[(size_t)(k0 + j) * HE_ + c]);
    *(s16x8*)(wp + (size_t)gid * 8) = pk;
    return;
  }

  // ---- k1 branch (fp32 attn needed for the 0.1 hard threshold)
  int bid2 = bid - NG_PACK;
  int b = (bid2 & 7) * 4 + (bid2 >> 7);      // XCD-grouped (null but harmless)
  int t0 = ((bid2 >> 3) & 15) * 8;
  int bt0 = b * T_ + t0;
  const float* reg = region + (size_t)b * R_ * D_;
  const float4* word4 = (const float4*)word;
  int il = lane & 15, g = lane >> 4;

  // word slices: quad q's token = q*4+g; float4 index il + kq*16 (interleaved)
  float4 wv[2][8];
#pragma unroll
  for (int q = 0; q < 2; ++q)
#pragma unroll
    for (int kq = 0; kq < 8; ++kq)
      wv[q][kq] = word4[(size_t)(bt0 + q * 4 + g) * 128 + il + kq * 16];

  for (int r = wave; r < R_; r += 8) {
    const float4* rrow4 = (const float4*)(reg + (size_t)r * D_);
    float4 rv[8];
#pragma unroll
    for (int kq = 0; kq < 8; ++kq) rv[kq] = rrow4[il + kq * 16];
    // stage bf16 copy for the pos phase (group 0 only: groups 1-3 loaded the
    // SAME float4s). Lane il writes 8B at byte 8*il+128*kq within the row:
    // 16 lanes x 32 distinct banks -> conflict-free.
    if (g == 0) {
#pragma unroll
      for (int kq = 0; kq < 8; ++kq) {
        s16x4 pk;
        pk[0] = (short)bf16rne(rv[kq].x);
        pk[1] = (short)bf16rne(rv[kq].y);
        pk[2] = (short)bf16rne(rv[kq].z);
        pk[3] = (short)bf16rne(rv[kq].w);
        *(s16x4*)&regs_bf[r * D_ + 4 * (il + kq * 16)] = pk;
      }
    }
#pragma unroll
    for (int q = 0; q < 2; ++q) {
      float acc = 0.f;
#pragma unroll
      for (int kq = 0; kq < 8; ++kq) {
        float4 w = wv[q][kq], rr = rv[kq];
        acc = fmaf(w.x, rr.x, acc);
        acc = fmaf(w.y, rr.y, acc);
        acc = fmaf(w.z, rr.z, acc);
        acc = fmaf(w.w, rr.w, acc);
      }
      // 4-deep chain reduces all 4 groups (tokens) at once
      acc += __shfl_xor(acc, 8);
      acc += __shfl_xor(acc, 4);
      acc += __shfl_xor(acc, 2);
      acc += __shfl_xor(acc, 1);
      if (il == 0) attn_s[q * 4 + g][r] = acc;
    }
  }
  __syncthreads();

  {
    int t = wave;  // 8 waves, one token each
    int am = amask[bt0 + t];
    float a = (lane < R_) ? attn_s[t][lane] : 0.f;
    float neg = (lane < R_ && (a - 0.1f) > 0.f) ? 1.f : 0.f;
    float masked = (lane < R_) ? ((neg > 0.f) ? a * 4.0f : -4e9f) : -3.0e38f;
    float cnt = wave_sum(neg);
    float m = masked;
#pragma unroll
    for (int off = 32; off; off >>= 1) m = fmaxf(m, __shfl_down(m, off));
    m = __shfl(m, 0);
    float e = (lane < R_) ? __expf(masked - m) : 0.f;
    float s = wave_sum(e);
    s = __shfl(s, 0);
    if (lane < R_) wp_T[lane][t] = e / s;
    bool want = (lane < R_) && (neg == 0.f) && (am != 0);
    unsigned long long bm = __ballot(want);
    if (lane == 0) {
      negcnt[bt0 + t] = cnt;
      nmask[bt0 + t] = bm;
    }
  }
  __syncthreads();

  // pos: thread owns d = tid; region read from LDS (bf16) -> no global
  // latency chain (the old 49x global dword chain was k1's dominant stall).
  int d = tid;
  float accs[8] = {0.f, 0.f, 0.f, 0.f, 0.f, 0.f, 0.f, 0.f};
#pragma unroll 7
  for (int r = 0; r < R_; ++r) {
    float gg = bf16tof(regs_bf[r * D_ + d]);
    float4 w0 = *(const float4*)&wp_T[r][0];
    float4 w1 = *(const float4*)&wp_T[r][4];
    accs[0] = fmaf(w0.x, gg, accs[0]);
    accs[1] = fmaf(w0.y, gg, accs[1]);
    accs[2] = fmaf(w0.z, gg, accs[2]);
    accs[3] = fmaf(w0.w, gg, accs[3]);
    accs[4] = fmaf(w1.x, gg, accs[4]);
    accs[5] = fmaf(w1.y, gg, accs[5]);
    accs[6] = fmaf(w1.z, gg, accs[6]);
    accs[7] = fmaf(w1.w, gg, accs[7]);
  }
#pragma unroll
  for (int t = 0; t < 8; ++t) {
    size_t base = (size_t)(bt0 + t) * D_ + d;
    pos[base] = word[base] + accs[t];
  }
}

// ---------------------------------------------------------------------------
// K2: all MFMA GEMMs, 32-row tiles (unchanged from R8).
// ---------------------------------------------------------------------------
__global__ __launch_bounds__(512) void gemm_all(
    const float* __restrict__ word, const float* __restrict__ region,
    const float* __restrict__ pos, const unsigned short* __restrict__ wpack,
    const float* __restrict__ nb1, const float* __restrict__ pb1,
    const float* __restrict__ pw2, const float* __restrict__ pb2,
    const float* __restrict__ negcnt, const int* __restrict__ amask,
    float* __restrict__ wh, float* __restrict__ rh,
    float* __restrict__ pscore) {
  __shared__ alignas(16) unsigned short As[32 * 512];  // 32 KB; also hp[32][256] f32
  __shared__ float sred[32][4];
  int tid = threadIdx.x, wave = tid >> 6, lane = tid & 63;
  int bid = blockIdx.x;

  bool isg2 = (bid >= NG_G1);
  const float* A;
  float* outp = nullptr;
  int row0;
  bool useb = false;
  const s16x8* Wp8;
  if (!isg2) {
    if (bid < 128) {
      A = word; outp = wh; row0 = bid * 32; useb = true;
    } else {
      A = region; outp = rh; row0 = (bid - 128) * 32;
    }
    Wp8 = (const s16x8*)wpack;  // mat 0 = nw1
  } else {
    A = pos; row0 = (bid - NG_G1) * 32;
    Wp8 = (const s16x8*)wpack + 16384;  // mat 1 = pw1
  }
  const float4* A4 = (const float4*)(A + (size_t)row0 * D_);
#pragma unroll
  for (int it = 0; it < 8; ++it) {
    int f = it * 512 + tid;  // 0..4095: row 0..31, kq 0..127
    int row = f >> 7, kq = f & 127;
    float4 v = A4[f];
    int bo = (row * 1024 + kq * 8) ^ ((row & 7) << 4);
    s16x4 pk;
    pk[0] = (short)bf16rne(v.x);
    pk[1] = (short)bf16rne(v.y);
    pk[2] = (short)bf16rne(v.z);
    pk[3] = (short)bf16rne(v.w);
    *(s16x4*)((char*)As + bo) = pk;
  }
  __syncthreads();
  int rl = lane & 15, kg = lane >> 4;
  int ct0 = wave, ct1 = wave + 8;
  f32x4 acc[2][2];
#pragma unroll
  for (int s = 0; s < 2; ++s)
#pragma unroll
    for (int ci = 0; ci < 2; ++ci) acc[s][ci] = (f32x4){0.f, 0.f, 0.f, 0.f};
#pragma unroll
  for (int kt = 0; kt < 16; ++kt) {
    s16x8 b0 = Wp8[(size_t)(kt * 16 + ct0) * 64 + lane];
    s16x8 b1 = Wp8[(size_t)(kt * 16 + ct1) * 64 + lane];
#pragma unroll
    for (int sub = 0; sub < 2; ++sub) {
      int bo = ((sub * 16 + rl) * 1024 + kt * 64 + kg * 16) ^ ((rl & 7) << 4);
      s16x8 af = *(const s16x8*)((char*)As + bo);
      acc[sub][0] = __builtin_amdgcn_mfma_f32_16x16x32_bf16(af, b0, acc[sub][0], 0, 0, 0);
      acc[sub][1] = __builtin_amdgcn_mfma_f32_16x16x32_bf16(af, b1, acc[sub][1], 0, 0, 0);
    }
  }
  // C/D layout (m89-verified): col = lane&15, row = (lane>>4)*4 + reg
  if (!isg2) {
    float bb0 = useb ? nb1[ct0 * 16 + rl] : 0.f;
    float bb1 = useb ? nb1[ct1 * 16 + rl] : 0.f;
#pragma unroll
    for (int sub = 0; sub < 2; ++sub) {
      int r0 = row0 + sub * 16 + kg * 4;
#pragma unroll
      for (int q = 0; q < 4; ++q) {
        outp[(size_t)(r0 + q) * HE_ + ct0 * 16 + rl] = acc[sub][0][q] + bb0;
        outp[(size_t)(r0 + q) * HE_ + ct1 * 16 + rl] = acc[sub][1][q] + bb1;
      }
    }
    return;
  }
  __syncthreads();  // all A-tile reads done; reuse LDS for hp
  float* hp_s = (float*)As;  // [32][256] fp32 = 32 KB
#pragma unroll
  for (int sub = 0; sub < 2; ++sub)
#pragma unroll
    for (int q = 0; q < 4; ++q) {
      hp_s[(sub * 16 + kg * 4 + q) * 256 + ct0 * 16 + rl] = acc[sub][0][q];
      hp_s[(sub * 16 + kg * 4 + q) * 256 + ct1 * 16 + rl] = acc[sub][1][q];
    }
  __syncthreads();
  int c = tid & 255, jh = tid >> 8;  // jh = 0/1: 16 j-rows each
  float pb1c = pb1[c], pw2c = pw2[c];
#pragma unroll
  for (int jj = 0; jj < 16; ++jj) {
    int j = jh * 16 + jj;
    float v = tanh_fast(hp_s[j * 256 + c] + pb1c) * pw2c;
    v = wave_sum(v);
    if (lane == 0) sred[j][wave & 3] = v;
  }
  __syncthreads();
  if (tid < 32) {
    float s = sred[tid][0] + sred[tid][1] + sred[tid][2] + sred[tid][3] +
              pb2[0];
    s = sigmoid_fast(s);
    int row = row0 + tid;
    if (negcnt[row] == 0.f) s = 0.f;
    s *= (float)amask[row];
    pscore[row] = fmaxf(s, 0.f);
  }
}

// ---------------------------------------------------------------------------
// K3: LDS-tiled neg-expert (unchanged from R10).
// ---------------------------------------------------------------------------
__global__ __launch_bounds__(512, 6) void neg_expert(
    const float* __restrict__ wh, const float* __restrict__ rh,
    const float* __restrict__ nw2, const float* __restrict__ nb2,
    const unsigned long long* __restrict__ nmask, float* __restrict__ nst,
    float* __restrict__ nsr_sl) {
  __shared__ alignas(16) float rh_s[R_ * HE_];  // 49 KB
  __shared__ int plist[400];
  __shared__ float nst_l[8];
  __shared__ float nsr_l[52];
  __shared__ int cnt_s[8];
  __shared__ int off_s[8];
  __shared__ int P_s;
  int tid = threadIdx.x, wave = tid >> 6, lane = tid & 63;
  int nb = blockIdx.x;
  int b = (nb & 7) * 4 + (nb >> 7);          // XCD-grouped (see k1 header)
  int tile = (nb >> 3) & 15;
  int t0 = tile * 8;
  int bt0 = b * T_ + t0;
  int slot = b * 16 + tile;                  // nsr slice index (b-major)
  {
    const float4* src = (const float4*)(rh + (size_t)b * R_ * HE_);
    float4* dst = (float4*)rh_s;
    for (int i = tid; i < R_ * (HE_ / 4); i += 512) dst[i] = src[i];
  }
  if (tid < 8) {
    nst_l[tid] = 0.f;
    cnt_s[tid] = __popcll(nmask[bt0 + tid]);
  }
  if (tid < R_) nsr_l[tid] = 0.f;
  __syncthreads();
  if (tid == 0) {
    int tot = 0;
#pragma unroll
    for (int w = 0; w < 8; ++w) {
      off_s[w] = tot;
      tot += cnt_s[w];
    }
    P_s = tot;
  }
  __syncthreads();
  {
    unsigned long long mw = nmask[bt0 + wave];
    if (lane < R_ && ((mw >> lane) & 1ull)) {
      int pfx = __popcll(mw & ((1ull << lane) - 1ull));
      plist[off_s[wave] + pfx] = (wave << 6) | lane;
    }
  }
  __syncthreads();
  int P = P_s;
  int grp = tid >> 4, gl = tid & 15;
  float4 wnr[4];
#pragma unroll
  for (int k = 0; k < 4; ++k)
    wnr[k] = ((const float4*)nw2)[4 * gl + ((gl + k) & 3)];
  float bias = nb2[0];
  for (int i = grp; i < P; i += 32) {
    int tr = plist[i];
    int t = tr >> 6, r = tr & 63;
    const float4* wrow = (const float4*)(wh + (size_t)(bt0 + t) * HE_);
    const float4* rrow = (const float4*)(rh_s + r * HE_);
    float acc = 0.f;
#pragma unroll
    for (int k = 0; k < 4; ++k) {
      int c = 4 * gl + ((gl + k) & 3);  // rotation: 16 lanes hit all 32 banks
      float4 hw = wrow[c];              // global, L1/L2-hot
      float4 hr = rrow[c];              // LDS
      float4 wn = wnr[k];
      acc = fmaf(tanh_fast(hw.x + hr.x), wn.x, acc);
      acc = fmaf(tanh_fast(hw.y + hr.y), wn.y, acc);
      acc = fmaf(tanh_fast(hw.z + hr.z), wn.z, acc);
      acc = fmaf(tanh_fast(hw.w + hr.w), wn.w, acc);
    }
    acc += __shfl_xor(acc, 1);
    acc += __shfl_xor(acc, 2);
    acc += __shfl_xor(acc, 4);
    acc += __shfl_xor(acc, 8);
    if (gl == 0) {
      float s = sigmoid_fast(acc + bias);  // relu(sigmoid) == sigmoid
      atomicAdd(&nst_l[t], s);   // LDS atomics only
      atomicAdd(&nsr_l[r], s);
    }
  }
  __syncthreads();
  if (tid < 8) {
    nst[bt0 + tid] = nst_l[tid];
  } else if (tid >= 64 && tid < 64 + R_) {
    nsr_sl[(size_t)slot * R_ + (tid - 64)] = nsr_l[tid - 64];  // plain store
  }
}

// ---------------------------------------------------------------------------
// K4: aggregates; nsr reconstructed by summing the 16 per-tile slices.
// ---------------------------------------------------------------------------
__global__ __launch_bounds__(512) void k7a_agg(
    const float* __restrict__ word, const float* __restrict__ region,
    const float* __restrict__ pos, const float* __restrict__ pscore,
    const float* __restrict__ nst, const float* __restrict__ nsr_sl,
    float* __restrict__ nagg, float* __restrict__ pagg) {
  int b = blockIdx.x >> 3, dc = blockIdx.x & 7;
  int tid = threadIdx.x;
  int dl = tid & 63, ts = tid >> 6;
  int d = dc * 64 + dl;
  __shared__ float nst_s[T_], psc_s[T_], nsr_s[R_];
  __shared__ float redn[8][64], redp[8][64];
  if (tid < T_) {
    psc_s[tid] = pscore[b * T_ + tid];
    nst_s[tid] = nst[b * T_ + tid];
  } else if (tid < T_ + R_) {
    int r = tid - T_;
    float s = 0.f;
#pragma unroll
    for (int tt = 0; tt < 16; ++tt)
      s += nsr_sl[(size_t)(b * 16 + tt) * R_ + r];
    nsr_s[r] = s;
  }
  __syncthreads();
  float na = 0.f, pa = 0.f;
  for (int t = ts; t < T_; t += 8) {
    size_t base = ((size_t)(b * T_ + t)) * D_ + d;
    na = fmaf(nst_s[t], word[base], na);
    pa = fmaf(psc_s[t], pos[base], pa);
  }
  for (int r = ts; r < R_; r += 8)
    na = fmaf(nsr_s[r], region[((size_t)(b * R_ + r)) * D_ + d], na);
  redn[ts][dl] = na;
  redp[ts][dl] = pa;
  __syncthreads();
  if (tid < 64) {
    float s = 0.f;
#pragma unroll
    for (int k = 0; k < 8; ++k) s += redn[k][tid];
    nagg[(size_t)b * D_ + dc * 64 + tid] = s;
  } else if (tid < 128) {
    int l = tid - 64;
    float s = 0.f;
#pragma unroll
    for (int k = 0; k < 8; ++k) s += redp[k][l];
    pagg[(size_t)b * D_ + dc * 64 + l] = s;
  }
}

// ---------------------------------------------------------------------------
// K5: per-batch tail: choose, path_prob, final, classifier.
// ---------------------------------------------------------------------------
__global__ __launch_bounds__(256) void k7b_tail(
    const float* __restrict__ nagg, const float* __restrict__ pagg,
    const float* __restrict__ negcnt, const float* __restrict__ fcw,
    const float* __restrict__ fcb, const float* __restrict__ cw1,
    const float* __restrict__ cb1, const float* __restrict__ cw2,
    const float* __restrict__ cb2, float* __restrict__ out) {
  int b = blockIdx.x, tid = threadIdx.x, lane = tid & 63, wave = tid >> 6;
  __shared__ float na_s[D_], pa_s[D_], fin[D_];
  __shared__ float red[8];
  __shared__ float pp0, pp1;
  float cntp = (tid < T_) ? negcnt[b * T_ + tid] : 0.f;
  float cw = wave_sum(cntp);
  if (lane == 0) red[wave] = cw;
  int d0 = tid, d1 = tid + 256;
  float n0 = nagg[(size_t)b * D_ + d0], n1 = nagg[(size_t)b * D_ + d1];
  float p0 = pagg[(size_t)b * D_ + d0], p1 = pagg[(size_t)b * D_ + d1];
  na_s[d0] = n0;
  na_s[d1] = n1;
  pa_s[d0] = p0;
  pa_s[d1] = p1;
  __syncthreads();
  float cnt_total = red[0] + red[1] + red[2] + red[3];
  float f0 = fcw[d0], f1 = fcw[d1];
  float c0p = n0 * f0 + n1 * f1;
  float c1p = p0 * f0 + p1 * f1;
  c0p = wave_sum(c0p);
  c1p = wave_sum(c1p);
  __syncthreads();
  if (lane == 0) { red[wave] = c0p; red[wave + 4] = c1p; }
  __syncthreads();
  if (tid == 0) {
    float c0 = red[0] + red[1] + red[2] + red[3] + fcb[0];
    float c1 = red[4] + red[5] + red[6] + red[7] + fcb[0];
    if (cnt_total == 0.f) c0 = -1e9f;
    float m = fmaxf(c0, c1);
    float e0 = __expf(c0 - m), e1 = __expf(c1 - m);
    float inv = 1.f / (e0 + e1);
    pp0 = e0 * inv;
    pp1 = e1 * inv;
    out[2 * B_ + 2 * b + 0] = pp0;
    out[2 * B_ + 2 * b + 1] = pp1;
  }
  __syncthreads();
  for (int d = tid; d < D_; d += 256) fin[d] = pp0 * na_s[d] + pp1 * pa_s[d];
  __syncthreads();
  float a0 = cb1[tid], a1 = 0.f, a2 = 0.f, a3 = 0.f;
#pragma unroll 4
  for (int d = 0; d < D_; d += 4) {
    a0 = fmaf(fin[d + 0], cw1[(size_t)(d + 0) * HC_ + tid], a0);
    a1 = fmaf(fin[d + 1], cw1[(size_t)(d + 1) * HC_ + tid], a1);
    a2 = fmaf(fin[d + 2], cw1[(size_t)(d + 2) * HC_ + tid], a2);
    a3 = fmaf(fin[d + 3], cw1[(size_t)(d + 3) * HC_ + tid], a3);
  }
  float acc = fmaxf((a0 + a1) + (a2 + a3), 0.f);
  float l0 = acc * cw2[2 * tid + 0];
  float l1 = acc * cw2[2 * tid + 1];
  l0 = wave_sum(l0);
  l1 = wave_sum(l1);
  __syncthreads();
  if (lane == 0) { red[wave] = l0; red[wave + 4] = l1; }
  __syncthreads();
  if (tid == 0) {
    out[2 * b + 0] = red[0] + red[1] + red[2] + red[3] + cb2[0];
    out[2 * b + 1] = red[4] + red[5] + red[6] + red[7] + cb2[1];
  }
}

extern "C" void kernel_launch(void* const* d_in, const int* in_sizes, int n_in,
                              void* d_out, int out_size, void* d_ws,
                              size_t ws_size, hipStream_t stream) {
  const float* word = (const float*)d_in[0];
  const float* region = (const float*)d_in[1];
  const int* amask = (const int*)d_in[2];
  const float* pw1 = (const float*)d_in[3];
  const float* pb1 = (const float*)d_in[4];
  const float* pw2 = (const float*)d_in[5];
  const float* pb2 = (const float*)d_in[6];
  const float* nw1 = (const float*)d_in[7];
  const float* nb1 = (const float*)d_in[8];
  const float* nw2 = (const float*)d_in[9];
  const float* nb2 = (const float*)d_in[10];
  const float* fcw = (const float*)d_in[11];
  const float* fcb = (const float*)d_in[12];
  const float* cw1 = (const float*)d_in[13];
  const float* cb1 = (const float*)d_in[14];
  const float* cw2 = (const float*)d_in[15];
  const float* cb2 = (const float*)d_in[16];
  float* out = (float*)d_out;

  unsigned short* wpack = (unsigned short*)d_ws;  // 2*131072 bf16 = 512 KB
  float* ws = (float*)d_ws + 131072;
  float* pos = ws;                              // B*T*D
  float* wh = pos + (size_t)B_ * T_ * D_;       // B*T*HE
  float* rh = wh + (size_t)B_ * T_ * HE_;       // B*R*HE
  float* nst = rh + (size_t)B_ * R_ * HE_;      // B*T
  float* nsr_sl = nst + (size_t)B_ * T_;        // B*16*R per-tile slices
  float* negcnt = nsr_sl + (size_t)B_ * 16 * R_;  // B*T
  float* pscore = negcnt + B_ * T_;             // B*T
  float* nagg = pscore + B_ * T_;               // B*D
  float* pagg = nagg + (size_t)B_ * D_;         // B*D
  unsigned long long* nmask =
      (unsigned long long*)(pagg + (size_t)B_ * D_);  // B*T (8B each)

  k1_pack<<<NG_PACK + NG_K1, 512, 0, stream>>>(
      word, region, nw1, pw1, amask, wpack, pos, negcnt, nmask);
  gemm_all<<<NG_G1 + NG_G2, 512, 0, stream>>>(
      word, region, pos, wpack, nb1, pb1, pw2, pb2, negcnt, amask, wh, rh,
      pscore);
  neg_expert<<<NG_NEGB, 512, 0, stream>>>(wh, rh, nw2, nb2, nmask, nst,
                                          nsr_sl);
  k7a_agg<<<B_ * 8, 512, 0, stream>>>(word, region, pos, pscore, nst, nsr_sl,
                                      nagg, pagg);
  k7b_tail<<<B_, 256, 0, stream>>>(nagg, pagg, negcnt, fcw, fcb, cw1, cb1,
                                   cw2, cb2, out);
}

// Round 12
// 77.162 us; speedup vs baseline: 1.0136x; 1.0136x over previous
//
#include <hip/hip_runtime.h>

#define B_ 32
#define T_ 128
#define R_ 49
#define D_ 512
#define HE_ 256
#define HC_ 256

#define NG_PACK 64     // pack blocks folded into K1 (independent of k1 work)
#define NG_K1 256      // k1: 16 tokens per block (R12: was 8/512)
#define NG_G1 177      // 128 wh-tiles + 49 rh-tiles (32 rows each)
#define NG_G2 128      // pscore GEMM tiles (32 rows each)
#define NG_NEGB 512    // neg-expert: one block per (b, 8-token tile)

typedef float f32x4 __attribute__((ext_vector_type(4)));
typedef short s16x8 __attribute__((ext_vector_type(8)));
typedef short s16x4 __attribute__((ext_vector_type(4)));

__device__ __forceinline__ unsigned short bf16rne(float f) {
  unsigned u = __float_as_uint(f);
  u += 0x7FFF + ((u >> 16) & 1);
  return (unsigned short)(u >> 16);
}
__device__ __forceinline__ float rcp_fast(float x) {
  return __builtin_amdgcn_rcpf(x);
}
__device__ __forceinline__ float tanh_fast(float x) {
  float e = __expf(2.0f * x);
  return fmaf(-2.0f, rcp_fast(e + 1.0f), 1.0f);
}
__device__ __forceinline__ float sigmoid_fast(float x) {
  return rcp_fast(1.0f + __expf(-x));
}
__device__ __forceinline__ float wave_sum(float v) {
#pragma unroll
  for (int off = 32; off; off >>= 1) v += __shfl_down(v, off);
  return v;  // total valid in lane 0
}

// ---------------------------------------------------------------------------
// K1: pack blocks (bid<64) + k1 blocks (attn/softmax/pos).
// R12: 16 tokens per block (256 blocks). Rationale (R9 PMC): k1 fetched
// 39MB/pass vs ~11MB unique at 1.5TB/s == its 26.6us duration -> bound by
// aggregate region re-fetch (region[b]=100KB read whole by every token
// tile; 512 tiles -> 51MB demanded; 64 blocks/XCD x 100KB = 6.4MB > 4MiB
// L2 -> structural thrash; R10's swizzle couldn't fix capacity). Doubling
// tokens/block halves the demand (25.6MB) and shrinks the per-XCD set to
// 3.2MB < L2, so the pos phase re-reads now hit L2. Each region row in
// registers feeds 4 token-quads (wv[4][8] ~ 128 VGPR; launch_bounds(512,2)).
// Attn dot + softmax are bit-identical per token to the passing R8 form.
// ---------------------------------------------------------------------------
__global__ __launch_bounds__(512, 2) void k1_pack(
    const float* __restrict__ word, const float* __restrict__ region,
    const float* __restrict__ nw1, const float* __restrict__ pw1,
    const int* __restrict__ amask, unsigned short* __restrict__ wp,
    float* __restrict__ pos, float* __restrict__ negcnt,
    unsigned long long* __restrict__ nmask) {
  __shared__ float attn_s[16][52];
  __shared__ alignas(16) float wp_T[49][16];
  int tid = threadIdx.x, wave = tid >> 6, lane = tid & 63;
  int bid = blockIdx.x;

  if (bid < NG_PACK) {
    int gid = bid * 512 + tid;  // 0..32767
    int mat = gid >> 14;
    int rem = gid & 16383;
    int plane = rem & 63;
    int tile = rem >> 6;
    int kt = tile >> 4, ct = tile & 15;
    const float* W = mat ? pw1 : nw1;
    int k0 = kt * 32 + (plane >> 4) * 8;
    int c = ct * 16 + (plane & 15);
    s16x8 pk;
#pragma unroll
    for (int j = 0; j < 8; ++j)
      pk[j] = (short)bf16rne(W[(size_t)(k0 + j) * HE_ + c]);
    *(s16x8*)(wp + (size_t)gid * 8) = pk;
    return;
  }

  // ---- k1 branch (fp32 attn needed for the 0.1 hard threshold)
  int bid2 = bid - NG_PACK;      // 0..255
  int b = bid2 >> 3;             // 8 tiles per b
  int t0 = (bid2 & 7) * 16;      // 16 tokens per tile
  int bt0 = b * T_ + t0;
  const float* reg = region + (size_t)b * R_ * D_;
  const float4* word4 = (const float4*)word;
  int il = lane & 15, g = lane >> 4;

  // word slices: quad q's token = q*4+g; float4 index il + kq*16 (each
  // 16-lane group collectively holds its 4 tokens' full rows).
  float4 wv[4][8];
#pragma unroll
  for (int q = 0; q < 4; ++q)
#pragma unroll
    for (int kq = 0; kq < 8; ++kq)
      wv[q][kq] = word4[(size_t)(bt0 + q * 4 + g) * 128 + il + kq * 16];

  for (int r = wave; r < R_; r += 8) {
    const float4* rrow4 = (const float4*)(reg + (size_t)r * D_);
    float4 rv[8];
#pragma unroll
    for (int kq = 0; kq < 8; ++kq) rv[kq] = rrow4[il + kq * 16];
#pragma unroll
    for (int q = 0; q < 4; ++q) {  // one region stream feeds 4 quads
      float acc = 0.f;
#pragma unroll
      for (int kq = 0; kq < 8; ++kq) {
        float4 w = wv[q][kq], rr = rv[kq];
        acc = fmaf(w.x, rr.x, acc);
        acc = fmaf(w.y, rr.y, acc);
        acc = fmaf(w.z, rr.z, acc);
        acc = fmaf(w.w, rr.w, acc);
      }
      // 4-deep chain reduces all 4 groups (tokens) at once
      acc += __shfl_xor(acc, 8);
      acc += __shfl_xor(acc, 4);
      acc += __shfl_xor(acc, 2);
      acc += __shfl_xor(acc, 1);
      if (il == 0) attn_s[q * 4 + g][r] = acc;
    }
  }
  __syncthreads();

#pragma unroll
  for (int th = 0; th < 2; ++th) {
    int t = wave + th * 8;  // 8 waves x 2 passes cover 16 tokens
    int am = amask[bt0 + t];
    float a = (lane < R_) ? attn_s[t][lane] : 0.f;
    float neg = (lane < R_ && (a - 0.1f) > 0.f) ? 1.f : 0.f;
    float masked = (lane < R_) ? ((neg > 0.f) ? a * 4.0f : -4e9f) : -3.0e38f;
    float cnt = wave_sum(neg);
    float m = masked;
#pragma unroll
    for (int off = 32; off; off >>= 1) m = fmaxf(m, __shfl_down(m, off));
    m = __shfl(m, 0);
    float e = (lane < R_) ? __expf(masked - m) : 0.f;
    float s = wave_sum(e);
    s = __shfl(s, 0);
    if (lane < R_) wp_T[lane][t] = e / s;
    bool want = (lane < R_) && (neg == 0.f) && (am != 0);
    unsigned long long bm = __ballot(want);
    if (lane == 0) {
      negcnt[bt0 + t] = cnt;
      nmask[bt0 + t] = bm;
    }
  }
  __syncthreads();

  // pos: thread owns d = tid (512 = D), 16 token accumulators; region rows
  // are L2-hot (3.2MB/XCD resident set after the 256-block regrid).
  int d = tid;
  float accs[16];
#pragma unroll
  for (int t = 0; t < 16; ++t) accs[t] = 0.f;
#pragma unroll 7
  for (int r = 0; r < R_; ++r) {
    float gg = reg[(size_t)r * D_ + d];
    float4 w0 = *(const float4*)&wp_T[r][0];
    float4 w1 = *(const float4*)&wp_T[r][4];
    float4 w2 = *(const float4*)&wp_T[r][8];
    float4 w3 = *(const float4*)&wp_T[r][12];
    accs[0] = fmaf(w0.x, gg, accs[0]);
    accs[1] = fmaf(w0.y, gg, accs[1]);
    accs[2] = fmaf(w0.z, gg, accs[2]);
    accs[3] = fmaf(w0.w, gg, accs[3]);
    accs[4] = fmaf(w1.x, gg, accs[4]);
    accs[5] = fmaf(w1.y, gg, accs[5]);
    accs[6] = fmaf(w1.z, gg, accs[6]);
    accs[7] = fmaf(w1.w, gg, accs[7]);
    accs[8] = fmaf(w2.x, gg, accs[8]);
    accs[9] = fmaf(w2.y, gg, accs[9]);
    accs[10] = fmaf(w2.z, gg, accs[10]);
    accs[11] = fmaf(w2.w, gg, accs[11]);
    accs[12] = fmaf(w3.x, gg, accs[12]);
    accs[13] = fmaf(w3.y, gg, accs[13]);
    accs[14] = fmaf(w3.z, gg, accs[14]);
    accs[15] = fmaf(w3.w, gg, accs[15]);
  }
#pragma unroll
  for (int t = 0; t < 16; ++t) {
    size_t base = (size_t)(bt0 + t) * D_ + d;
    pos[base] = word[base] + accs[t];
  }
}

// ---------------------------------------------------------------------------
// K2: all MFMA GEMMs, 32-row tiles (unchanged from R8).
// ---------------------------------------------------------------------------
__global__ __launch_bounds__(512) void gemm_all(
    const float* __restrict__ word, const float* __restrict__ region,
    const float* __restrict__ pos, const unsigned short* __restrict__ wpack,
    const float* __restrict__ nb1, const float* __restrict__ pb1,
    const float* __restrict__ pw2, const float* __restrict__ pb2,
    const float* __restrict__ negcnt, const int* __restrict__ amask,
    float* __restrict__ wh, float* __restrict__ rh,
    float* __restrict__ pscore) {
  __shared__ alignas(16) unsigned short As[32 * 512];  // 32 KB; also hp[32][256] f32
  __shared__ float sred[32][4];
  int tid = threadIdx.x, wave = tid >> 6, lane = tid & 63;
  int bid = blockIdx.x;

  bool isg2 = (bid >= NG_G1);
  const float* A;
  float* outp = nullptr;
  int row0;
  bool useb = false;
  const s16x8* Wp8;
  if (!isg2) {
    if (bid < 128) {
      A = word; outp = wh; row0 = bid * 32; useb = true;
    } else {
      A = region; outp = rh; row0 = (bid - 128) * 32;
    }
    Wp8 = (const s16x8*)wpack;  // mat 0 = nw1
  } else {
    A = pos; row0 = (bid - NG_G1) * 32;
    Wp8 = (const s16x8*)wpack + 16384;  // mat 1 = pw1
  }
  const float4* A4 = (const float4*)(A + (size_t)row0 * D_);
#pragma unroll
  for (int it = 0; it < 8; ++it) {
    int f = it * 512 + tid;  // 0..4095: row 0..31, kq 0..127
    int row = f >> 7, kq = f & 127;
    float4 v = A4[f];
    int bo = (row * 1024 + kq * 8) ^ ((row & 7) << 4);
    s16x4 pk;
    pk[0] = (short)bf16rne(v.x);
    pk[1] = (short)bf16rne(v.y);
    pk[2] = (short)bf16rne(v.z);
    pk[3] = (short)bf16rne(v.w);
    *(s16x4*)((char*)As + bo) = pk;
  }
  __syncthreads();
  int rl = lane & 15, kg = lane >> 4;
  int ct0 = wave, ct1 = wave + 8;
  f32x4 acc[2][2];
#pragma unroll
  for (int s = 0; s < 2; ++s)
#pragma unroll
    for (int ci = 0; ci < 2; ++ci) acc[s][ci] = (f32x4){0.f, 0.f, 0.f, 0.f};
#pragma unroll
  for (int kt = 0; kt < 16; ++kt) {
    s16x8 b0 = Wp8[(size_t)(kt * 16 + ct0) * 64 + lane];
    s16x8 b1 = Wp8[(size_t)(kt * 16 + ct1) * 64 + lane];
#pragma unroll
    for (int sub = 0; sub < 2; ++sub) {
      int bo = ((sub * 16 + rl) * 1024 + kt * 64 + kg * 16) ^ ((rl & 7) << 4);
      s16x8 af = *(const s16x8*)((char*)As + bo);
      acc[sub][0] = __builtin_amdgcn_mfma_f32_16x16x32_bf16(af, b0, acc[sub][0], 0, 0, 0);
      acc[sub][1] = __builtin_amdgcn_mfma_f32_16x16x32_bf16(af, b1, acc[sub][1], 0, 0, 0);
    }
  }
  // C/D layout (m89-verified): col = lane&15, row = (lane>>4)*4 + reg
  if (!isg2) {
    float bb0 = useb ? nb1[ct0 * 16 + rl] : 0.f;
    float bb1 = useb ? nb1[ct1 * 16 + rl] : 0.f;
#pragma unroll
    for (int sub = 0; sub < 2; ++sub) {
      int r0 = row0 + sub * 16 + kg * 4;
#pragma unroll
      for (int q = 0; q < 4; ++q) {
        outp[(size_t)(r0 + q) * HE_ + ct0 * 16 + rl] = acc[sub][0][q] + bb0;
        outp[(size_t)(r0 + q) * HE_ + ct1 * 16 + rl] = acc[sub][1][q] + bb1;
      }
    }
    return;
  }
  __syncthreads();  // all A-tile reads done; reuse LDS for hp
  float* hp_s = (float*)As;  // [32][256] fp32 = 32 KB
#pragma unroll
  for (int sub = 0; sub < 2; ++sub)
#pragma unroll
    for (int q = 0; q < 4; ++q) {
      hp_s[(sub * 16 + kg * 4 + q) * 256 + ct0 * 16 + rl] = acc[sub][0][q];
      hp_s[(sub * 16 + kg * 4 + q) * 256 + ct1 * 16 + rl] = acc[sub][1][q];
    }
  __syncthreads();
  int c = tid & 255, jh = tid >> 8;  // jh = 0/1: 16 j-rows each
  float pb1c = pb1[c], pw2c = pw2[c];
#pragma unroll
  for (int jj = 0; jj < 16; ++jj) {
    int j = jh * 16 + jj;
    float v = tanh_fast(hp_s[j * 256 + c] + pb1c) * pw2c;
    v = wave_sum(v);
    if (lane == 0) sred[j][wave & 3] = v;
  }
  __syncthreads();
  if (tid < 32) {
    float s = sred[tid][0] + sred[tid][1] + sred[tid][2] + sred[tid][3] +
              pb2[0];
    s = sigmoid_fast(s);
    int row = row0 + tid;
    if (negcnt[row] == 0.f) s = 0.f;
    s *= (float)amask[row];
    pscore[row] = fmaxf(s, 0.f);
  }
}

// ---------------------------------------------------------------------------
// K3: LDS-tiled neg-expert (unchanged; passing form).
// ---------------------------------------------------------------------------
__global__ __launch_bounds__(512, 6) void neg_expert(
    const float* __restrict__ wh, const float* __restrict__ rh,
    const float* __restrict__ nw2, const float* __restrict__ nb2,
    const unsigned long long* __restrict__ nmask, float* __restrict__ nst,
    float* __restrict__ nsr_sl) {
  __shared__ alignas(16) float rh_s[R_ * HE_];  // 49 KB
  __shared__ int plist[400];
  __shared__ float nst_l[8];
  __shared__ float nsr_l[52];
  __shared__ int cnt_s[8];
  __shared__ int off_s[8];
  __shared__ int P_s;
  int tid = threadIdx.x, wave = tid >> 6, lane = tid & 63;
  int nb = blockIdx.x;
  int b = (nb & 7) * 4 + (nb >> 7);          // XCD-grouped (harmless)
  int tile = (nb >> 3) & 15;
  int t0 = tile * 8;
  int bt0 = b * T_ + t0;
  int slot = b * 16 + tile;                  // nsr slice index (b-major)
  {
    const float4* src = (const float4*)(rh + (size_t)b * R_ * HE_);
    float4* dst = (float4*)rh_s;
    for (int i = tid; i < R_ * (HE_ / 4); i += 512) dst[i] = src[i];
  }
  if (tid < 8) {
    nst_l[tid] = 0.f;
    cnt_s[tid] = __popcll(nmask[bt0 + tid]);
  }
  if (tid < R_) nsr_l[tid] = 0.f;
  __syncthreads();
  if (tid == 0) {
    int tot = 0;
#pragma unroll
    for (int w = 0; w < 8; ++w) {
      off_s[w] = tot;
      tot += cnt_s[w];
    }
    P_s = tot;
  }
  __syncthreads();
  {
    unsigned long long mw = nmask[bt0 + wave];
    if (lane < R_ && ((mw >> lane) & 1ull)) {
      int pfx = __popcll(mw & ((1ull << lane) - 1ull));
      plist[off_s[wave] + pfx] = (wave << 6) | lane;
    }
  }
  __syncthreads();
  int P = P_s;
  int grp = tid >> 4, gl = tid & 15;
  float4 wnr[4];
#pragma unroll
  for (int k = 0; k < 4; ++k)
    wnr[k] = ((const float4*)nw2)[4 * gl + ((gl + k) & 3)];
  float bias = nb2[0];
  for (int i = grp; i < P; i += 32) {
    int tr = plist[i];
    int t = tr >> 6, r = tr & 63;
    const float4* wrow = (const float4*)(wh + (size_t)(bt0 + t) * HE_);
    const float4* rrow = (const float4*)(rh_s + r * HE_);
    float acc = 0.f;
#pragma unroll
    for (int k = 0; k < 4; ++k) {
      int c = 4 * gl + ((gl + k) & 3);  // rotation: 16 lanes hit all 32 banks
      float4 hw = wrow[c];              // global, L1/L2-hot
      float4 hr = rrow[c];              // LDS
      float4 wn = wnr[k];
      acc = fmaf(tanh_fast(hw.x + hr.x), wn.x, acc);
      acc = fmaf(tanh_fast(hw.y + hr.y), wn.y, acc);
      acc = fmaf(tanh_fast(hw.z + hr.z), wn.z, acc);
      acc = fmaf(tanh_fast(hw.w + hr.w), wn.w, acc);
    }
    acc += __shfl_xor(acc, 1);
    acc += __shfl_xor(acc, 2);
    acc += __shfl_xor(acc, 4);
    acc += __shfl_xor(acc, 8);
    if (gl == 0) {
      float s = sigmoid_fast(acc + bias);  // relu(sigmoid) == sigmoid
      atomicAdd(&nst_l[t], s);   // LDS atomics only
      atomicAdd(&nsr_l[r], s);
    }
  }
  __syncthreads();
  if (tid < 8) {
    nst[bt0 + tid] = nst_l[tid];
  } else if (tid >= 64 && tid < 64 + R_) {
    nsr_sl[(size_t)slot * R_ + (tid - 64)] = nsr_l[tid - 64];  // plain store
  }
}

// ---------------------------------------------------------------------------
// K4: aggregates; nsr reconstructed by summing the 16 per-tile slices.
// ---------------------------------------------------------------------------
__global__ __launch_bounds__(512) void k7a_agg(
    const float* __restrict__ word, const float* __restrict__ region,
    const float* __restrict__ pos, const float* __restrict__ pscore,
    const float* __restrict__ nst, const float* __restrict__ nsr_sl,
    float* __restrict__ nagg, float* __restrict__ pagg) {
  int b = blockIdx.x >> 3, dc = blockIdx.x & 7;
  int tid = threadIdx.x;
  int dl = tid & 63, ts = tid >> 6;
  int d = dc * 64 + dl;
  __shared__ float nst_s[T_], psc_s[T_], nsr_s[R_];
  __shared__ float redn[8][64], redp[8][64];
  if (tid < T_) {
    psc_s[tid] = pscore[b * T_ + tid];
    nst_s[tid] = nst[b * T_ + tid];
  } else if (tid < T_ + R_) {
    int r = tid - T_;
    float s = 0.f;
#pragma unroll
    for (int tt = 0; tt < 16; ++tt)
      s += nsr_sl[(size_t)(b * 16 + tt) * R_ + r];
    nsr_s[r] = s;
  }
  __syncthreads();
  float na = 0.f, pa = 0.f;
  for (int t = ts; t < T_; t += 8) {
    size_t base = ((size_t)(b * T_ + t)) * D_ + d;
    na = fmaf(nst_s[t], word[base], na);
    pa = fmaf(psc_s[t], pos[base], pa);
  }
  for (int r = ts; r < R_; r += 8)
    na = fmaf(nsr_s[r], region[((size_t)(b * R_ + r)) * D_ + d], na);
  redn[ts][dl] = na;
  redp[ts][dl] = pa;
  __syncthreads();
  if (tid < 64) {
    float s = 0.f;
#pragma unroll
    for (int k = 0; k < 8; ++k) s += redn[k][tid];
    nagg[(size_t)b * D_ + dc * 64 + tid] = s;
  } else if (tid < 128) {
    int l = tid - 64;
    float s = 0.f;
#pragma unroll
    for (int k = 0; k < 8; ++k) s += redp[k][l];
    pagg[(size_t)b * D_ + dc * 64 + l] = s;
  }
}

// ---------------------------------------------------------------------------
// K5: per-batch tail: choose, path_prob, final, classifier.
// ---------------------------------------------------------------------------
__global__ __launch_bounds__(256) void k7b_tail(
    const float* __restrict__ nagg, const float* __restrict__ pagg,
    const float* __restrict__ negcnt, const float* __restrict__ fcw,
    const float* __restrict__ fcb, const float* __restrict__ cw1,
    const float* __restrict__ cb1, const float* __restrict__ cw2,
    const float* __restrict__ cb2, float* __restrict__ out) {
  int b = blockIdx.x, tid = threadIdx.x, lane = tid & 63, wave = tid >> 6;
  __shared__ float na_s[D_], pa_s[D_], fin[D_];
  __shared__ float red[8];
  __shared__ float pp0, pp1;
  float cntp = (tid < T_) ? negcnt[b * T_ + tid] : 0.f;
  float cw = wave_sum(cntp);
  if (lane == 0) red[wave] = cw;
  int d0 = tid, d1 = tid + 256;
  float n0 = nagg[(size_t)b * D_ + d0], n1 = nagg[(size_t)b * D_ + d1];
  float p0 = pagg[(size_t)b * D_ + d0], p1 = pagg[(size_t)b * D_ + d1];
  na_s[d0] = n0;
  na_s[d1] = n1;
  pa_s[d0] = p0;
  pa_s[d1] = p1;
  __syncthreads();
  float cnt_total = red[0] + red[1] + red[2] + red[3];
  float f0 = fcw[d0], f1 = fcw[d1];
  float c0p = n0 * f0 + n1 * f1;
  float c1p = p0 * f0 + p1 * f1;
  c0p = wave_sum(c0p);
  c1p = wave_sum(c1p);
  __syncthreads();
  if (lane == 0) { red[wave] = c0p; red[wave + 4] = c1p; }
  __syncthreads();
  if (tid == 0) {
    float c0 = red[0] + red[1] + red[2] + red[3] + fcb[0];
    float c1 = red[4] + red[5] + red[6] + red[7] + fcb[0];
    if (cnt_total == 0.f) c0 = -1e9f;
    float m = fmaxf(c0, c1);
    float e0 = __expf(c0 - m), e1 = __expf(c1 - m);
    float inv = 1.f / (e0 + e1);
    pp0 = e0 * inv;
    pp1 = e1 * inv;
    out[2 * B_ + 2 * b + 0] = pp0;
    out[2 * B_ + 2 * b + 1] = pp1;
  }
  __syncthreads();
  for (int d = tid; d < D_; d += 256) fin[d] = pp0 * na_s[d] + pp1 * pa_s[d];
  __syncthreads();
  float a0 = cb1[tid], a1 = 0.f, a2 = 0.f, a3 = 0.f;
#pragma unroll 4
  for (int d = 0; d < D_; d += 4) {
    a0 = fmaf(fin[d + 0], cw1[(size_t)(d + 0) * HC_ + tid], a0);
    a1 = fmaf(fin[d + 1], cw1[(size_t)(d + 1) * HC_ + tid], a1);
    a2 = fmaf(fin[d + 2], cw1[(size_t)(d + 2) * HC_ + tid], a2);
    a3 = fmaf(fin[d + 3], cw1[(size_t)(d + 3) * HC_ + tid], a3);
  }
  float acc = fmaxf((a0 + a1) + (a2 + a3), 0.f);
  float l0 = acc * cw2[2 * tid + 0];
  float l1 = acc * cw2[2 * tid + 1];
  l0 = wave_sum(l0);
  l1 = wave_sum(l1);
  __syncthreads();
  if (lane == 0) { red[wave] = l0; red[wave + 4] = l1; }
  __syncthreads();
  if (tid == 0) {
    out[2 * b + 0] = red[0] + red[1] + red[2] + red[3] + cb2[0];
    out[2 * b + 1] = red[4] + red[5] + red[6] + red[7] + cb2[1];
  }
}

extern "C" void kernel_launch(void* const* d_in, const int* in_sizes, int n_in,
                              void* d_out, int out_size, void* d_ws,
                              size_t ws_size, hipStream_t stream) {
  const float* word = (const float*)d_in[0];
  const float* region = (const float*)d_in[1];
  const int* amask = (const int*)d_in[2];
  const float* pw1 = (const float*)d_in[3];
  const float* pb1 = (const float*)d_in[4];
  const float* pw2 = (const float*)d_in[5];
  const float* pb2 = (const float*)d_in[6];
  const float* nw1 = (const float*)d_in[7];
  const float* nb1 = (const float*)d_in[8];
  const float* nw2 = (const float*)d_in[9];
  const float* nb2 = (const float*)d_in[10];
  const float* fcw = (const float*)d_in[11];
  const float* fcb = (const float*)d_in[12];
  const float* cw1 = (const float*)d_in[13];
  const float* cb1 = (const float*)d_in[14];
  const float* cw2 = (const float*)d_in[15];
  const float* cb2 = (const float*)d_in[16];
  float* out = (float*)d_out;

  unsigned short* wpack = (unsigned short*)d_ws;  // 2*131072 bf16 = 512 KB
  float* ws = (float*)d_ws + 131072;
  float* pos = ws;                              // B*T*D
  float* wh = pos + (size_t)B_ * T_ * D_;       // B*T*HE
  float* rh = wh + (size_t)B_ * T_ * HE_;       // B*R*HE
  float* nst = rh + (size_t)B_ * R_ * HE_;      // B*T
  float* nsr_sl = nst + (size_t)B_ * T_;        // B*16*R per-tile slices
  float* negcnt = nsr_sl + (size_t)B_ * 16 * R_;  // B*T
  float* pscore = negcnt + B_ * T_;             // B*T
  float* nagg = pscore + B_ * T_;               // B*D
  float* pagg = nagg + (size_t)B_ * D_;         // B*D
  unsigned long long* nmask =
      (unsigned long long*)(pagg + (size_t)B_ * D_);  // B*T (8B each)

  k1_pack<<<NG_PACK + NG_K1, 512, 0, stream>>>(
      word, region, nw1, pw1, amask, wpack, pos, negcnt, nmask);
  gemm_all<<<NG_G1 + NG_G2, 512, 0, stream>>>(
      word, region, pos, wpack, nb1, pb1, pw2, pb2, negcnt, amask, wh, rh,
      pscore);
  neg_expert<<<NG_NEGB, 512, 0, stream>>>(wh, rh, nw2, nb2, nmask, nst,
                                          nsr_sl);
  k7a_agg<<<B_ * 8, 512, 0, stream>>>(word, region, pos, pscore, nst, nsr_sl,
                                      nagg, pagg);
  k7b_tail<<<B_, 256, 0, stream>>>(nagg, pagg, negcnt, fcw, fcb, cw1, cb1,
                                   cw2, cb2, out);
}

// Round 13
// 74.580 us; speedup vs baseline: 1.0487x; 1.0346x over previous
//
#include <hip/hip_runtime.h>

#define B_ 32
#define T_ 128
#define R_ 49
#define D_ 512
#define HE_ 256
#define HC_ 256

#define NG_WHRH 177    // 128 wh-tiles + 49 rh-tiles (32 rows each), K1 bids 0-176
#define NG_K1 512      // k1: 8 tokens per block, K1 bids 177-688
#define NG_NEG 512     // neg-expert, K2 bids 0-511
#define NG_G2 128      // pscore GEMM tiles, K2 bids 512-639

typedef float f32x4 __attribute__((ext_vector_type(4)));
typedef short s16x8 __attribute__((ext_vector_type(8)));
typedef short s16x4 __attribute__((ext_vector_type(4)));

__device__ __forceinline__ unsigned short bf16rne(float f) {
  unsigned u = __float_as_uint(f);
  u += 0x7FFF + ((u >> 16) & 1);
  return (unsigned short)(u >> 16);
}
__device__ __forceinline__ float rcp_fast(float x) {
  return __builtin_amdgcn_rcpf(x);
}
__device__ __forceinline__ float tanh_fast(float x) {
  float e = __expf(2.0f * x);
  return fmaf(-2.0f, rcp_fast(e + 1.0f), 1.0f);
}
__device__ __forceinline__ float sigmoid_fast(float x) {
  return rcp_fast(1.0f + __expf(-x));
}
__device__ __forceinline__ float wave_sum(float v) {
#pragma unroll
  for (int off = 32; off; off >>= 1) v += __shfl_down(v, off);
  return v;  // total valid in lane 0
}

// ---------------------------------------------------------------------------
// pack_w: repack nw1 (mat0) / pw1 (mat1) [512][256] fp32 -> bf16 B-fragments,
// order [mat][kt16][ct16][lane64][j8]. Standalone again (R13): the wh/rh GEMM
// moved into K1 for stall-overlap with k1, so wpack must be stream-ready
// before K1. No workspace zeroing needed (all downstream writes are plain
// stores now).
// ---------------------------------------------------------------------------
__global__ __launch_bounds__(256) void pack_w(
    const float* __restrict__ nw1, const float* __restrict__ pw1,
    unsigned short* __restrict__ wp) {
  int gid = blockIdx.x * 256 + threadIdx.x;  // 0..32767
  int mat = gid >> 14;
  int rem = gid & 16383;
  int lane = rem & 63;
  int tile = rem >> 6;
  int kt = tile >> 4, ct = tile & 15;
  const float* W = mat ? pw1 : nw1;
  int k0 = kt * 32 + (lane >> 4) * 8;
  int c = ct * 16 + (lane & 15);
  s16x8 pk;
#pragma unroll
  for (int j = 0; j < 8; ++j)
    pk[j] = (short)bf16rne(W[(size_t)(k0 + j) * HE_ + c]);
  *(s16x8*)(wp + (size_t)gid * 8) = pk;
}

// ---------------------------------------------------------------------------
// K1: heterogeneous co-scheduling (R13). bids 0-176 = wh/rh MFMA-GEMM
// (independent of k1); bids 177-688 = k1 attn/softmax/pos (R8 form, byte-
// identical math). Both block families are >80% stall when run alone (R7/R9
// PMC); co-residency on a CU (2 blocks at 128 VGPR) lets each fill the
// other's memory-stall bubbles. whrh dispatched FIRST so round-1 CUs host
// one whrh + one k1 block.
// ---------------------------------------------------------------------------
__global__ __launch_bounds__(512, 4) void k1_whrh(
    const float* __restrict__ word, const float* __restrict__ region,
    const unsigned short* __restrict__ wpack, const float* __restrict__ nb1,
    const int* __restrict__ amask, float* __restrict__ wh,
    float* __restrict__ rh, float* __restrict__ pos,
    float* __restrict__ negcnt, unsigned long long* __restrict__ nmask) {
  __shared__ union SM1 {
    struct G {
      alignas(16) unsigned short As[32 * 512];  // 32 KB
    } g;
    struct K {
      float attn_s[8][52];
      alignas(16) float wp_T[49][8];
    } k;
  } sm;
  int tid = threadIdx.x, wave = tid >> 6, lane = tid & 63;
  int bid = blockIdx.x;

  if (bid < NG_WHRH) {
    // ---- wh/rh GEMM branch (R8 32-row tiles, verbatim) ----
    const float* A;
    float* outp;
    int row0;
    bool useb;
    if (bid < 128) {
      A = word; outp = wh; row0 = bid * 32; useb = true;
    } else {
      A = region; outp = rh; row0 = (bid - 128) * 32; useb = false;
    }
    const s16x8* Wp8 = (const s16x8*)wpack;  // mat 0 = nw1
    const float4* A4 = (const float4*)(A + (size_t)row0 * D_);
#pragma unroll
    for (int it = 0; it < 8; ++it) {
      int f = it * 512 + tid;  // row 0..31, kq 0..127
      int row = f >> 7, kq = f & 127;
      float4 v = A4[f];
      int bo = (row * 1024 + kq * 8) ^ ((row & 7) << 4);
      s16x4 pk;
      pk[0] = (short)bf16rne(v.x);
      pk[1] = (short)bf16rne(v.y);
      pk[2] = (short)bf16rne(v.z);
      pk[3] = (short)bf16rne(v.w);
      *(s16x4*)((char*)sm.g.As + bo) = pk;
    }
    __syncthreads();
    int rl = lane & 15, kg = lane >> 4;
    int ct0 = wave, ct1 = wave + 8;
    f32x4 acc[2][2];
#pragma unroll
    for (int s = 0; s < 2; ++s)
#pragma unroll
      for (int ci = 0; ci < 2; ++ci) acc[s][ci] = (f32x4){0.f, 0.f, 0.f, 0.f};
#pragma unroll
    for (int kt = 0; kt < 16; ++kt) {
      s16x8 b0 = Wp8[(size_t)(kt * 16 + ct0) * 64 + lane];
      s16x8 b1 = Wp8[(size_t)(kt * 16 + ct1) * 64 + lane];
#pragma unroll
      for (int sub = 0; sub < 2; ++sub) {
        int bo = ((sub * 16 + rl) * 1024 + kt * 64 + kg * 16) ^ ((rl & 7) << 4);
        s16x8 af = *(const s16x8*)((char*)sm.g.As + bo);
        acc[sub][0] = __builtin_amdgcn_mfma_f32_16x16x32_bf16(af, b0, acc[sub][0], 0, 0, 0);
        acc[sub][1] = __builtin_amdgcn_mfma_f32_16x16x32_bf16(af, b1, acc[sub][1], 0, 0, 0);
      }
    }
    // C/D layout (m89-verified): col = lane&15, row = (lane>>4)*4 + reg
    float bb0 = useb ? nb1[ct0 * 16 + rl] : 0.f;
    float bb1 = useb ? nb1[ct1 * 16 + rl] : 0.f;
#pragma unroll
    for (int sub = 0; sub < 2; ++sub) {
      int r0 = row0 + sub * 16 + kg * 4;
#pragma unroll
      for (int q = 0; q < 4; ++q) {
        outp[(size_t)(r0 + q) * HE_ + ct0 * 16 + rl] = acc[sub][0][q] + bb0;
        outp[(size_t)(r0 + q) * HE_ + ct1 * 16 + rl] = acc[sub][1][q] + bb1;
      }
    }
    return;
  }

  // ---- k1 branch (R8 form verbatim; fp32 attn for the 0.1 hard threshold)
  int bid2 = bid - NG_WHRH;
  int b = bid2 >> 4;
  int t0 = (bid2 & 15) * 8;
  int bt0 = b * T_ + t0;
  const float* reg = region + (size_t)b * R_ * D_;
  const float4* word4 = (const float4*)word;
  int il = lane & 15, g = lane >> 4;

  float4 wv[2][8];
#pragma unroll
  for (int q = 0; q < 2; ++q)
#pragma unroll
    for (int kq = 0; kq < 8; ++kq)
      wv[q][kq] = word4[(size_t)(bt0 + q * 4 + g) * 128 + il + kq * 16];

  for (int r = wave; r < R_; r += 8) {
    const float4* rrow4 = (const float4*)(reg + (size_t)r * D_);
    float4 rv[8];
#pragma unroll
    for (int kq = 0; kq < 8; ++kq) rv[kq] = rrow4[il + kq * 16];
#pragma unroll
    for (int q = 0; q < 2; ++q) {
      float acc = 0.f;
#pragma unroll
      for (int kq = 0; kq < 8; ++kq) {
        float4 w = wv[q][kq], rr = rv[kq];
        acc = fmaf(w.x, rr.x, acc);
        acc = fmaf(w.y, rr.y, acc);
        acc = fmaf(w.z, rr.z, acc);
        acc = fmaf(w.w, rr.w, acc);
      }
      acc += __shfl_xor(acc, 8);
      acc += __shfl_xor(acc, 4);
      acc += __shfl_xor(acc, 2);
      acc += __shfl_xor(acc, 1);
      if (il == 0) sm.k.attn_s[q * 4 + g][r] = acc;
    }
  }
  __syncthreads();

  {
    int t = wave;  // 8 waves, one token each
    int am = amask[bt0 + t];
    float a = (lane < R_) ? sm.k.attn_s[t][lane] : 0.f;
    float neg = (lane < R_ && (a - 0.1f) > 0.f) ? 1.f : 0.f;
    float masked = (lane < R_) ? ((neg > 0.f) ? a * 4.0f : -4e9f) : -3.0e38f;
    float cnt = wave_sum(neg);
    float m = masked;
#pragma unroll
    for (int off = 32; off; off >>= 1) m = fmaxf(m, __shfl_down(m, off));
    m = __shfl(m, 0);
    float e = (lane < R_) ? __expf(masked - m) : 0.f;
    float s = wave_sum(e);
    s = __shfl(s, 0);
    if (lane < R_) sm.k.wp_T[lane][t] = e / s;
    bool want = (lane < R_) && (neg == 0.f) && (am != 0);
    unsigned long long bm = __ballot(want);
    if (lane == 0) {
      negcnt[bt0 + t] = cnt;
      nmask[bt0 + t] = bm;
    }
  }
  __syncthreads();

  // pos: thread owns d = tid (512 = D), 8 token accumulators
  int d = tid;
  float accs[8] = {0.f, 0.f, 0.f, 0.f, 0.f, 0.f, 0.f, 0.f};
#pragma unroll 7
  for (int r = 0; r < R_; ++r) {
    float gg = reg[(size_t)r * D_ + d];
    float4 w0 = *(const float4*)&sm.k.wp_T[r][0];
    float4 w1 = *(const float4*)&sm.k.wp_T[r][4];
    accs[0] = fmaf(w0.x, gg, accs[0]);
    accs[1] = fmaf(w0.y, gg, accs[1]);
    accs[2] = fmaf(w0.z, gg, accs[2]);
    accs[3] = fmaf(w0.w, gg, accs[3]);
    accs[4] = fmaf(w1.x, gg, accs[4]);
    accs[5] = fmaf(w1.y, gg, accs[5]);
    accs[6] = fmaf(w1.z, gg, accs[6]);
    accs[7] = fmaf(w1.w, gg, accs[7]);
  }
#pragma unroll
  for (int t = 0; t < 8; ++t) {
    size_t base = (size_t)(bt0 + t) * D_ + d;
    pos[base] = word[base] + accs[t];
  }
}

// ---------------------------------------------------------------------------
// K2: heterogeneous co-scheduling, part 2. bids 0-511 = LDS-tiled neg-expert
// (the long pole, ~13us alone); bids 512-639 = pscore GEMM (~5us alone,
// hides under neg). LDS union keeps the block footprint at 51 KB -> 3/CU.
// ---------------------------------------------------------------------------
__global__ __launch_bounds__(512, 4) void neg_g2(
    const float* __restrict__ pos, const unsigned short* __restrict__ wpack,
    const float* __restrict__ pb1, const float* __restrict__ pw2,
    const float* __restrict__ pb2, const float* __restrict__ negcnt,
    const int* __restrict__ amask, const float* __restrict__ wh,
    const float* __restrict__ rh, const float* __restrict__ nw2,
    const float* __restrict__ nb2,
    const unsigned long long* __restrict__ nmask, float* __restrict__ pscore,
    float* __restrict__ nst, float* __restrict__ nsr_sl) {
  __shared__ union SM2 {
    struct G {
      alignas(16) unsigned short As[32 * 512];  // 32 KB; reused as hp f32
      float sred[32][4];
    } g;
    struct N {
      alignas(16) float rh_s[R_ * HE_];  // 49 KB
      int plist[400];
      float nst_l[8];
      float nsr_l[52];
      int cnt_s[8];
      int off_s[8];
      int P;
    } n;
  } sm;
  int tid = threadIdx.x, wave = tid >> 6, lane = tid & 63;
  int bid = blockIdx.x;

  if (bid >= NG_NEG) {
    // ---- pscore GEMM branch (R8 isg2 path, verbatim) ----
    int row0 = (bid - NG_NEG) * 32;
    const s16x8* Wp8 = (const s16x8*)wpack + 16384;  // mat 1 = pw1
    const float4* A4 = (const float4*)(pos + (size_t)row0 * D_);
#pragma unroll
    for (int it = 0; it < 8; ++it) {
      int f = it * 512 + tid;
      int row = f >> 7, kq = f & 127;
      float4 v = A4[f];
      int bo = (row * 1024 + kq * 8) ^ ((row & 7) << 4);
      s16x4 pk;
      pk[0] = (short)bf16rne(v.x);
      pk[1] = (short)bf16rne(v.y);
      pk[2] = (short)bf16rne(v.z);
      pk[3] = (short)bf16rne(v.w);
      *(s16x4*)((char*)sm.g.As + bo) = pk;
    }
    __syncthreads();
    int rl = lane & 15, kg = lane >> 4;
    int ct0 = wave, ct1 = wave + 8;
    f32x4 acc[2][2];
#pragma unroll
    for (int s = 0; s < 2; ++s)
#pragma unroll
      for (int ci = 0; ci < 2; ++ci) acc[s][ci] = (f32x4){0.f, 0.f, 0.f, 0.f};
#pragma unroll
    for (int kt = 0; kt < 16; ++kt) {
      s16x8 b0 = Wp8[(size_t)(kt * 16 + ct0) * 64 + lane];
      s16x8 b1 = Wp8[(size_t)(kt * 16 + ct1) * 64 + lane];
#pragma unroll
      for (int sub = 0; sub < 2; ++sub) {
        int bo = ((sub * 16 + rl) * 1024 + kt * 64 + kg * 16) ^ ((rl & 7) << 4);
        s16x8 af = *(const s16x8*)((char*)sm.g.As + bo);
        acc[sub][0] = __builtin_amdgcn_mfma_f32_16x16x32_bf16(af, b0, acc[sub][0], 0, 0, 0);
        acc[sub][1] = __builtin_amdgcn_mfma_f32_16x16x32_bf16(af, b1, acc[sub][1], 0, 0, 0);
      }
    }
    __syncthreads();  // all A-tile reads done; reuse LDS for hp
    float* hp_s = (float*)sm.g.As;  // [32][256] fp32 = 32 KB
#pragma unroll
    for (int sub = 0; sub < 2; ++sub)
#pragma unroll
      for (int q = 0; q < 4; ++q) {
        hp_s[(sub * 16 + kg * 4 + q) * 256 + ct0 * 16 + rl] = acc[sub][0][q];
        hp_s[(sub * 16 + kg * 4 + q) * 256 + ct1 * 16 + rl] = acc[sub][1][q];
      }
    __syncthreads();
    int c = tid & 255, jh = tid >> 8;
    float pb1c = pb1[c], pw2c = pw2[c];
#pragma unroll
    for (int jj = 0; jj < 16; ++jj) {
      int j = jh * 16 + jj;
      float v = tanh_fast(hp_s[j * 256 + c] + pb1c) * pw2c;
      v = wave_sum(v);
      if (lane == 0) sm.g.sred[j][wave & 3] = v;
    }
    __syncthreads();
    if (tid < 32) {
      float s = sm.g.sred[tid][0] + sm.g.sred[tid][1] + sm.g.sred[tid][2] +
                sm.g.sred[tid][3] + pb2[0];
      s = sigmoid_fast(s);
      int row = row0 + tid;
      if (negcnt[row] == 0.f) s = 0.f;
      s *= (float)amask[row];
      pscore[row] = fmaxf(s, 0.f);
    }
    return;
  }

  // ---- neg-expert branch (R10 form, plain b mapping) ----
  int nb = bid;
  int b = nb >> 4, tile = nb & 15;
  int t0 = tile * 8;
  int bt0 = b * T_ + t0;
  {
    const float4* src = (const float4*)(rh + (size_t)b * R_ * HE_);
    float4* dst = (float4*)sm.n.rh_s;
    for (int i = tid; i < R_ * (HE_ / 4); i += 512) dst[i] = src[i];
  }
  if (tid < 8) {
    sm.n.nst_l[tid] = 0.f;
    sm.n.cnt_s[tid] = __popcll(nmask[bt0 + tid]);
  }
  if (tid < R_) sm.n.nsr_l[tid] = 0.f;
  __syncthreads();
  if (tid == 0) {
    int tot = 0;
#pragma unroll
    for (int w = 0; w < 8; ++w) {
      sm.n.off_s[w] = tot;
      tot += sm.n.cnt_s[w];
    }
    sm.n.P = tot;
  }
  __syncthreads();
  {
    unsigned long long mw = nmask[bt0 + wave];
    if (lane < R_ && ((mw >> lane) & 1ull)) {
      int pfx = __popcll(mw & ((1ull << lane) - 1ull));
      sm.n.plist[sm.n.off_s[wave] + pfx] = (wave << 6) | lane;
    }
  }
  __syncthreads();
  int P = sm.n.P;
  int grp = tid >> 4, gl = tid & 15;
  float4 wnr[4];
#pragma unroll
  for (int k = 0; k < 4; ++k)
    wnr[k] = ((const float4*)nw2)[4 * gl + ((gl + k) & 3)];
  float bias = nb2[0];
  for (int i = grp; i < P; i += 32) {
    int tr = sm.n.plist[i];
    int t = tr >> 6, r = tr & 63;
    const float4* wrow = (const float4*)(wh + (size_t)(bt0 + t) * HE_);
    const float4* rrow = (const float4*)(sm.n.rh_s + r * HE_);
    float acc = 0.f;
#pragma unroll
    for (int k = 0; k < 4; ++k) {
      int c = 4 * gl + ((gl + k) & 3);  // rotation: 16 lanes hit all 32 banks
      float4 hw = wrow[c];              // global, L1/L2-hot
      float4 hr = rrow[c];              // LDS
      float4 wn = wnr[k];
      acc = fmaf(tanh_fast(hw.x + hr.x), wn.x, acc);
      acc = fmaf(tanh_fast(hw.y + hr.y), wn.y, acc);
      acc = fmaf(tanh_fast(hw.z + hr.z), wn.z, acc);
      acc = fmaf(tanh_fast(hw.w + hr.w), wn.w, acc);
    }
    acc += __shfl_xor(acc, 1);
    acc += __shfl_xor(acc, 2);
    acc += __shfl_xor(acc, 4);
    acc += __shfl_xor(acc, 8);
    if (gl == 0) {
      float s = sigmoid_fast(acc + bias);  // relu(sigmoid) == sigmoid
      atomicAdd(&sm.n.nst_l[t], s);   // LDS atomics only
      atomicAdd(&sm.n.nsr_l[r], s);
    }
  }
  __syncthreads();
  if (tid < 8) {
    nst[bt0 + tid] = sm.n.nst_l[tid];
  } else if (tid >= 64 && tid < 64 + R_) {
    nsr_sl[(size_t)nb * R_ + (tid - 64)] = sm.n.nsr_l[tid - 64];  // plain store
  }
}

// ---------------------------------------------------------------------------
// K4: aggregates; nsr reconstructed by summing the 16 per-tile slices.
// ---------------------------------------------------------------------------
__global__ __launch_bounds__(512) void k7a_agg(
    const float* __restrict__ word, const float* __restrict__ region,
    const float* __restrict__ pos, const float* __restrict__ pscore,
    const float* __restrict__ nst, const float* __restrict__ nsr_sl,
    float* __restrict__ nagg, float* __restrict__ pagg) {
  int b = blockIdx.x >> 3, dc = blockIdx.x & 7;
  int tid = threadIdx.x;
  int dl = tid & 63, ts = tid >> 6;
  int d = dc * 64 + dl;
  __shared__ float nst_s[T_], psc_s[T_], nsr_s[R_];
  __shared__ float redn[8][64], redp[8][64];
  if (tid < T_) {
    psc_s[tid] = pscore[b * T_ + tid];
    nst_s[tid] = nst[b * T_ + tid];
  } else if (tid < T_ + R_) {
    int r = tid - T_;
    float s = 0.f;
#pragma unroll
    for (int tt = 0; tt < 16; ++tt)
      s += nsr_sl[(size_t)(b * 16 + tt) * R_ + r];
    nsr_s[r] = s;
  }
  __syncthreads();
  float na = 0.f, pa = 0.f;
  for (int t = ts; t < T_; t += 8) {
    size_t base = ((size_t)(b * T_ + t)) * D_ + d;
    na = fmaf(nst_s[t], word[base], na);
    pa = fmaf(psc_s[t], pos[base], pa);
  }
  for (int r = ts; r < R_; r += 8)
    na = fmaf(nsr_s[r], region[((size_t)(b * R_ + r)) * D_ + d], na);
  redn[ts][dl] = na;
  redp[ts][dl] = pa;
  __syncthreads();
  if (tid < 64) {
    float s = 0.f;
#pragma unroll
    for (int k = 0; k < 8; ++k) s += redn[k][tid];
    nagg[(size_t)b * D_ + dc * 64 + tid] = s;
  } else if (tid < 128) {
    int l = tid - 64;
    float s = 0.f;
#pragma unroll
    for (int k = 0; k < 8; ++k) s += redp[k][l];
    pagg[(size_t)b * D_ + dc * 64 + l] = s;
  }
}

// ---------------------------------------------------------------------------
// K5: per-batch tail: choose, path_prob, final, classifier.
// ---------------------------------------------------------------------------
__global__ __launch_bounds__(256) void k7b_tail(
    const float* __restrict__ nagg, const float* __restrict__ pagg,
    const float* __restrict__ negcnt, const float* __restrict__ fcw,
    const float* __restrict__ fcb, const float* __restrict__ cw1,
    const float* __restrict__ cb1, const float* __restrict__ cw2,
    const float* __restrict__ cb2, float* __restrict__ out) {
  int b = blockIdx.x, tid = threadIdx.x, lane = tid & 63, wave = tid >> 6;
  __shared__ float na_s[D_], pa_s[D_], fin[D_];
  __shared__ float red[8];
  __shared__ float pp0, pp1;
  float cntp = (tid < T_) ? negcnt[b * T_ + tid] : 0.f;
  float cw = wave_sum(cntp);
  if (lane == 0) red[wave] = cw;
  int d0 = tid, d1 = tid + 256;
  float n0 = nagg[(size_t)b * D_ + d0], n1 = nagg[(size_t)b * D_ + d1];
  float p0 = pagg[(size_t)b * D_ + d0], p1 = pagg[(size_t)b * D_ + d1];
  na_s[d0] = n0;
  na_s[d1] = n1;
  pa_s[d0] = p0;
  pa_s[d1] = p1;
  __syncthreads();
  float cnt_total = red[0] + red[1] + red[2] + red[3];
  float f0 = fcw[d0], f1 = fcw[d1];
  float c0p = n0 * f0 + n1 * f1;
  float c1p = p0 * f0 + p1 * f1;
  c0p = wave_sum(c0p);
  c1p = wave_sum(c1p);
  __syncthreads();
  if (lane == 0) { red[wave] = c0p; red[wave + 4] = c1p; }
  __syncthreads();
  if (tid == 0) {
    float c0 = red[0] + red[1] + red[2] + red[3] + fcb[0];
    float c1 = red[4] + red[5] + red[6] + red[7] + fcb[0];
    if (cnt_total == 0.f) c0 = -1e9f;
    float m = fmaxf(c0, c1);
    float e0 = __expf(c0 - m), e1 = __expf(c1 - m);
    float inv = 1.f / (e0 + e1);
    pp0 = e0 * inv;
    pp1 = e1 * inv;
    out[2 * B_ + 2 * b + 0] = pp0;
    out[2 * B_ + 2 * b + 1] = pp1;
  }
  __syncthreads();
  for (int d = tid; d < D_; d += 256) fin[d] = pp0 * na_s[d] + pp1 * pa_s[d];
  __syncthreads();
  float a0 = cb1[tid], a1 = 0.f, a2 = 0.f, a3 = 0.f;
#pragma unroll 4
  for (int d = 0; d < D_; d += 4) {
    a0 = fmaf(fin[d + 0], cw1[(size_t)(d + 0) * HC_ + tid], a0);
    a1 = fmaf(fin[d + 1], cw1[(size_t)(d + 1) * HC_ + tid], a1);
    a2 = fmaf(fin[d + 2], cw1[(size_t)(d + 2) * HC_ + tid], a2);
    a3 = fmaf(fin[d + 3], cw1[(size_t)(d + 3) * HC_ + tid], a3);
  }
  float acc = fmaxf((a0 + a1) + (a2 + a3), 0.f);
  float l0 = acc * cw2[2 * tid + 0];
  float l1 = acc * cw2[2 * tid + 1];
  l0 = wave_sum(l0);
  l1 = wave_sum(l1);
  __syncthreads();
  if (lane == 0) { red[wave] = l0; red[wave + 4] = l1; }
  __syncthreads();
  if (tid == 0) {
    out[2 * b + 0] = red[0] + red[1] + red[2] + red[3] + cb2[0];
    out[2 * b + 1] = red[4] + red[5] + red[6] + red[7] + cb2[1];
  }
}

extern "C" void kernel_launch(void* const* d_in, const int* in_sizes, int n_in,
                              void* d_out, int out_size, void* d_ws,
                              size_t ws_size, hipStream_t stream) {
  const float* word = (const float*)d_in[0];
  const float* region = (const float*)d_in[1];
  const int* amask = (const int*)d_in[2];
  const float* pw1 = (const float*)d_in[3];
  const float* pb1 = (const float*)d_in[4];
  const float* pw2 = (const float*)d_in[5];
  const float* pb2 = (const float*)d_in[6];
  const float* nw1 = (const float*)d_in[7];
  const float* nb1 = (const float*)d_in[8];
  const float* nw2 = (const float*)d_in[9];
  const float* nb2 = (const float*)d_in[10];
  const float* fcw = (const float*)d_in[11];
  const float* fcb = (const float*)d_in[12];
  const float* cw1 = (const float*)d_in[13];
  const float* cb1 = (const float*)d_in[14];
  const float* cw2 = (const float*)d_in[15];
  const float* cb2 = (const float*)d_in[16];
  float* out = (float*)d_out;

  unsigned short* wpack = (unsigned short*)d_ws;  // 2*131072 bf16 = 512 KB
  float* ws = (float*)d_ws + 131072;
  float* pos = ws;                              // B*T*D
  float* wh = pos + (size_t)B_ * T_ * D_;       // B*T*HE
  float* rh = wh + (size_t)B_ * T_ * HE_;       // B*R*HE
  float* nst = rh + (size_t)B_ * R_ * HE_;      // B*T
  float* nsr_sl = nst + (size_t)B_ * T_;        // B*16*R per-tile slices
  float* negcnt = nsr_sl + (size_t)B_ * 16 * R_;  // B*T
  float* pscore = negcnt + B_ * T_;             // B*T
  float* nagg = pscore + B_ * T_;               // B*D
  float* pagg = nagg + (size_t)B_ * D_;         // B*D
  unsigned long long* nmask =
      (unsigned long long*)(pagg + (size_t)B_ * D_);  // B*T (8B each)

  pack_w<<<128, 256, 0, stream>>>(nw1, pw1, wpack);
  k1_whrh<<<NG_WHRH + NG_K1, 512, 0, stream>>>(
      word, region, wpack, nb1, amask, wh, rh, pos, negcnt, nmask);
  neg_g2<<<NG_NEG + NG_G2, 512, 0, stream>>>(
      pos, wpack, pb1, pw2, pb2, negcnt, amask, wh, rh, nw2, nb2, nmask,
      pscore, nst, nsr_sl);
  k7a_agg<<<B_ * 8, 512, 0, stream>>>(word, region, pos, pscore, nst, nsr_sl,
                                      nagg, pagg);
  k7b_tail<<<B_, 256, 0, stream>>>(nagg, pagg, negcnt, fcw, fcb, cw1, cb1,
                                   cw2, cb2, out);
}